// Round 9
// baseline (179.166 us; speedup 1.0000x reference)
//
#include <hip/hip_runtime.h>
#include <math.h>

#define B_ 4
#define S_ 2048
#define D_ 512
#define H_ 8
#define HD_ 64
#define RL_ 64
#define LN_EPS 1e-5f
#define SLOPE 0.01f
#define LOG2E 1.4426950408889634f

typedef __attribute__((ext_vector_type(8))) __bf16 bf16x8;
typedef __attribute__((ext_vector_type(4))) float f32x4;

__device__ __forceinline__ float leaky(float x) { return x >= 0.f ? x : SLOPE * x; }

// float -> bf16 (RNE)
__device__ __forceinline__ ushort f2bf(float f) {
    union { float f; unsigned u; } v; v.f = f;
    unsigned r = v.u + 0x7fffu + ((v.u >> 16) & 1u);
    return (ushort)(r >> 16);
}
__device__ __forceinline__ unsigned fbits(float f) {
    union { float f; unsigned u; } v; v.f = f; return v.u;
}

__device__ __forceinline__ void g2lds16(const void* g, void* l) {
    __builtin_amdgcn_global_load_lds(
        (const __attribute__((address_space(1))) void*)(uintptr_t)g,
        (__attribute__((address_space(3))) void*)(uintptr_t)l, 16, 0, 0);
}

// ---------------------------------------------------------------------------
// prep (merged): grid 4752
//   [0,4096) h f32->bf16   [4096,4608) rh->rhb
//   [4608,4736) Wr/Wf 64x64-tile transpose   [4736,4752) Wrs/Wrt transpose
// ---------------------------------------------------------------------------
__global__ __launch_bounds__(256) void prep(
    const float* __restrict__ h, const float* __restrict__ rh,
    const float* __restrict__ Wr, const float* __restrict__ Wf,
    const float* __restrict__ Wrs, const float* __restrict__ Wrt,
    ushort* __restrict__ hb, ushort* __restrict__ rhb,
    ushort* __restrict__ WrT, ushort* __restrict__ WfT,
    ushort* __restrict__ WrsT, ushort* __restrict__ WrtT)
{
    const int bx = blockIdx.x, tid = threadIdx.x;
    if (bx < 4608) {
        const float* in = (bx < 4096) ? h : rh;
        ushort* o = (bx < 4096) ? hb : rhb;
        const int i = (bx < 4096 ? bx : bx - 4096) * 256 + tid;
        const float4 v = ((const float4*)in)[i];
        ushort4 u; u.x = f2bf(v.x); u.y = f2bf(v.y); u.z = f2bf(v.z); u.w = f2bf(v.w);
        ((ushort4*)o)[i] = u;
        return;
    }
    __shared__ float TS[64][65];
    int t = bx - 4608;
    const float* in; ushort* out; int K, tk, tn;
    if (t < 64)       { in = Wr;  out = WrT;  K = 512; tk = t & 7; tn = t >> 3; }
    else if (t < 128) { in = Wf;  out = WfT;  K = 512; t -= 64; tk = t & 7; tn = t >> 3; }
    else if (t < 136) { in = Wrs; out = WrsT; K = 64;  tk = 0; tn = t - 128; }
    else              { in = Wrt; out = WrtT; K = 64;  tk = 0; tn = t - 136; }
    const int k0 = tk * 64, n0 = tn * 64;
    const int r = tid >> 4, c4 = (tid & 15) * 4;
    #pragma unroll
    for (int p = 0; p < 4; ++p) {
        const int row = r + 16 * p;
        const float4 v = *(const float4*)(in + (size_t)(k0 + row) * 512 + n0 + c4);
        TS[row][c4] = v.x; TS[row][c4 + 1] = v.y;
        TS[row][c4 + 2] = v.z; TS[row][c4 + 3] = v.w;
    }
    __syncthreads();
    #pragma unroll
    for (int p = 0; p < 4; ++p) {
        const int nn = r + 16 * p;
        ushort4 o;
        o.x = f2bf(TS[c4 + 0][nn]); o.y = f2bf(TS[c4 + 1][nn]);
        o.z = f2bf(TS[c4 + 2][nn]); o.w = f2bf(TS[c4 + 3][nn]);
        *(ushort4*)(out + (size_t)(n0 + nn) * K + k0 + c4) = o;
    }
}

// ---------------------------------------------------------------------------
// proj (fused): grid (128,4,3). z=0: fr-proj (K=512) -> frT + sr; z=1: rk;
// z=2: rq. 64x128 tile. A-operand: global->REGISTER with explicit register
// double-buffer (latency off the barrier-drain chain). B: LDS double-buffered
// via global_load_lds, R8-proven chunk swizzle.
// ---------------------------------------------------------------------------
__global__ __launch_bounds__(256) void proj(
    const ushort* __restrict__ hb, const ushort* __restrict__ rhb,
    const ushort* __restrict__ WrT, const ushort* __restrict__ WrsT,
    const ushort* __restrict__ WrtT,
    ushort* __restrict__ frT, ushort* __restrict__ rkw, ushort* __restrict__ rqw,
    float* __restrict__ sred, const float* __restrict__ ar)
{
    __shared__ ushort Bs[2][128 * 32];   // 16 KB

    const int tid = threadIdx.x;
    const int lane = tid & 63, w = tid >> 6;
    const int ln = lane & 15, quad = lane >> 4;
    const int wm = w >> 1, wn = w & 1;
    const int m0 = blockIdx.x * 64, n0 = blockIdx.y * 128;
    const int z = blockIdx.z;

    const ushort* A; const ushort* wt; ushort* co; float scl; int K;
    if (z == 0)      { A = hb;  wt = WrT;  co = frT; scl = LOG2E; K = 512; }
    else if (z == 1) { A = rhb; wt = WrsT; co = rkw; scl = LOG2E; K = 64; }
    else             { A = rhb; wt = WrtT; co = rqw; scl = 1.0f;  K = 64; }

    // B staging (R8-proven swizzle)
    const int srB = w * 32 + (lane >> 2);
    const int lchB = ((lane & 3) - (srB >> 1)) & 3;
    const ushort* BgB0 = wt + (size_t)(n0 + srB) * K + lchB * 8;
    const ushort* BgB1 = BgB0 + (size_t)16 * K;
    const int boff = srB * 32 + (lane & 3) * 8;
    const int pc = (quad + (ln >> 1)) & 3;

    // A rows (register-resident fragments)
    const ushort* Ar0 = A + (size_t)(m0 + wm * 32 + ln) * K + quad * 8;
    const ushort* Ar1 = A + (size_t)(m0 + wm * 32 + 16 + ln) * K + quad * 8;

    g2lds16(BgB0, &Bs[0][boff]);
    g2lds16(BgB1, &Bs[0][boff + 512]);
    bf16x8 a_cur[2], a_nxt[2];
    a_cur[0] = *(const bf16x8*)Ar0;
    a_cur[1] = *(const bf16x8*)Ar1;

    f32x4 acc[2][4] = {};
    int buf = 0;
    for (int k0 = 0; k0 < K; k0 += 32) {
        __syncthreads();
        if (k0 + 32 < K) {
            g2lds16(BgB0 + k0 + 32, &Bs[buf ^ 1][boff]);
            g2lds16(BgB1 + k0 + 32, &Bs[buf ^ 1][boff + 512]);
            a_nxt[0] = *(const bf16x8*)(Ar0 + k0 + 32);
            a_nxt[1] = *(const bf16x8*)(Ar1 + k0 + 32);
        }
        bf16x8 bfr[4];
        #pragma unroll
        for (int ni = 0; ni < 4; ++ni)
            bfr[ni] = *(const bf16x8*)&Bs[buf][(wn * 64 + ni * 16 + ln) * 32 + pc * 8];
        #pragma unroll
        for (int mi = 0; mi < 2; ++mi)
            #pragma unroll
            for (int ni = 0; ni < 4; ++ni)
                acc[mi][ni] = __builtin_amdgcn_mfma_f32_16x16x32_bf16(
                    a_cur[mi], bfr[ni], acc[mi][ni], 0, 0, 0);
        a_cur[0] = a_nxt[0]; a_cur[1] = a_nxt[1];
        buf ^= 1;
    }

    const int head = blockIdx.y * 2 + wn;
    const int b = m0 >> 11;
    const size_t bh = (size_t)b * H_ + head;
    if (z == 0) {
        #pragma unroll
        for (int mi = 0; mi < 2; ++mi) {
            const int s = (m0 & (S_ - 1)) + wm * 32 + mi * 16 + quad * 4;
            #pragma unroll
            for (int ni = 0; ni < 4; ++ni) {
                const int d = ni * 16 + ln;
                ushort4 o;
                o.x = f2bf(acc[mi][ni][0]); o.y = f2bf(acc[mi][ni][1]);
                o.z = f2bf(acc[mi][ni][2]); o.w = f2bf(acc[mi][ni][3]);
                *(ushort4*)(co + (bh * 64 + d) * S_ + s) = o;
            }
        }
        float a4[4];
        #pragma unroll
        for (int ni = 0; ni < 4; ++ni) a4[ni] = ar[ni * 16 + ln];
        #pragma unroll
        for (int mi = 0; mi < 2; ++mi) {
            const int s = (m0 & (S_ - 1)) + wm * 32 + mi * 16 + quad * 4;
            #pragma unroll
            for (int r = 0; r < 4; ++r) {
                float v = 0.f;
                #pragma unroll
                for (int ni = 0; ni < 4; ++ni)
                    v += leaky(acc[mi][ni][r]) * a4[ni];
                #pragma unroll
                for (int off = 8; off; off >>= 1) v += __shfl_xor(v, off, 16);
                if (ln == 0) sred[bh * S_ + s + r] = v * scl;
            }
        }
    } else {
        #pragma unroll
        for (int mi = 0; mi < 2; ++mi) {
            const int s = (m0 & (S_ - 1)) + wm * 32 + mi * 16 + quad * 4;
            #pragma unroll
            for (int ni = 0; ni < 4; ++ni) {
                const int d = ni * 16 + ln;
                #pragma unroll
                for (int r = 0; r < 4; ++r)
                    co[(bh * S_ + s + r) * 64 + d] = f2bf(acc[mi][ni][r] * scl);
            }
        }
    }
}

// ---------------------------------------------------------------------------
// Flash attention — unchanged from R8 (proven 56.9 µs).
// ---------------------------------------------------------------------------
__global__ __launch_bounds__(256, 2) void attn_mfma(
    const ushort* __restrict__ frT, const ushort* __restrict__ rk,
    const ushort* __restrict__ rq, const float* __restrict__ sr,
    ushort* __restrict__ hsa)
{
    __shared__ ushort RQ[2][64][64];
    __shared__ ushort FT[2][64][64];
    __shared__ ushort PS[8][16][64];

    const int tid = threadIdx.x;
    const int w = tid >> 6;
    const int lane = tid & 63;
    const int ln = lane & 15;
    const int quad = lane >> 4;
    const int b = blockIdx.z, h = blockIdx.y, q0 = blockIdx.x * 128;
    const size_t bh = (size_t)b * H_ + h;

    bf16x8 a[2][2];
    #pragma unroll
    for (int qs = 0; qs < 2; ++qs) {
        const ushort* p = rk + ((bh * S_ + q0 + 32 * w + 16 * qs + ln) << 6);
        a[qs][0] = *(const bf16x8*)(p + quad * 8);
        a[qs][1] = *(const bf16x8*)(p + 32 + quad * 8);
    }

    const ushort* rq_g = rq + (bh * S_ << 6);
    const ushort* ft_g = frT + (size_t)bh * 64 * S_;
    const float* srp = sr + bh * S_;

    const int rl = lane >> 3;
    const int pg = lane & 7;
    const int row_b = w * 16 + rl;
    const int sgF = (pg - rl) & 7;
    const int sgR0 = (pg - 4 * w - (rl >> 2)) & 7;
    const int sgR1 = (pg - 4 * w - 2 - (rl >> 2)) & 7;

    #define STAGE(BUF, t0)                                                    \
        {                                                                     \
            g2lds16(rq_g + ((size_t)((t0) + row_b) << 6) + sgR0 * 8,          \
                    &RQ[BUF][row_b][pg * 8]);                                 \
            g2lds16(rq_g + ((size_t)((t0) + row_b + 8) << 6) + sgR1 * 8,      \
                    &RQ[BUF][row_b + 8][pg * 8]);                             \
            g2lds16(ft_g + (size_t)row_b * S_ + (t0) + sgF * 8,               \
                    &FT[BUF][row_b][pg * 8]);                                 \
            g2lds16(ft_g + (size_t)(row_b + 8) * S_ + (t0) + sgF * 8,         \
                    &FT[BUF][row_b + 8][pg * 8]);                             \
        }

    const ushort* rqrA = &RQ[0][0][0] + 4 * ln * 64 + ((quad + ln) & 7) * 8;
    const ushort* rqrB = &RQ[0][0][0] + 4 * ln * 64 + ((quad + 4 + ln) & 7) * 8;
    const ushort* ftrA = &FT[0][0][0] + ln * 64 + ((quad + ln) & 7) * 8;
    const ushort* ftrB = &FT[0][0][0] + ln * 64 + ((quad + 4 + ln) & 7) * 8;
    ushort* sb[2];
    sb[0] = &PS[w * 2][0][0]; sb[1] = &PS[w * 2 + 1][0][0];
    int wr_off[4];
    #pragma unroll
    for (int r = 0; r < 4; ++r) {
        const int prow = quad * 4 + r;
        wr_off[r] = prow * 64 + (((ln >> 1) + prow) & 7) * 8 + (ln & 1) * 4;
    }
    const int rd0 = ln * 64 + ((quad + ln) & 7) * 8;
    const int rd1 = ln * 64 + ((quad + 4 + ln) & 7) * 8;

    STAGE(0, 0)
    __syncthreads();

    float lsum[2][4] = {};
    f32x4 ctx[2][4] = {};

    for (int t0 = 0; t0 < S_; t0 += 128) {
        #pragma unroll
        for (int half = 0; half < 2; ++half) {
            const int tc = t0 + 64 * half;
            if (tc + 64 < S_) {
                if (half == 0) STAGE(1, tc + 64)
                else           STAGE(0, tc + 64)
            }
            const float4 srv = *(const float4*)(srp + tc + 4 * ln);

            f32x4 sc[2][4];
            #pragma unroll
            for (int jb = 0; jb < 4; ++jb) {
                const bf16x8 b0 = *(const bf16x8*)(rqrA + half * 4096 + jb * 64);
                const bf16x8 b1 = *(const bf16x8*)(rqrB + half * 4096 + jb * 64);
                #pragma unroll
                for (int qs = 0; qs < 2; ++qs) {
                    f32x4 t = {0.f, 0.f, 0.f, 0.f};
                    t = __builtin_amdgcn_mfma_f32_16x16x32_bf16(a[qs][0], b0, t, 0, 0, 0);
                    t = __builtin_amdgcn_mfma_f32_16x16x32_bf16(a[qs][1], b1, t, 0, 0, 0);
                    sc[qs][jb] = t;
                }
            }

            #pragma unroll
            for (int qs = 0; qs < 2; ++qs)
                #pragma unroll
                for (int r = 0; r < 4; ++r) {
                    const float p0 = __builtin_amdgcn_exp2f(sc[qs][0][r] + srv.x);
                    const float p1 = __builtin_amdgcn_exp2f(sc[qs][1][r] + srv.y);
                    const float p2 = __builtin_amdgcn_exp2f(sc[qs][2][r] + srv.z);
                    const float p3 = __builtin_amdgcn_exp2f(sc[qs][3][r] + srv.w);
                    lsum[qs][r] += (p0 + p1) + (p2 + p3);
                    const unsigned lo = (fbits(p0) >> 16) | (fbits(p1) & 0xffff0000u);
                    const unsigned hi = (fbits(p2) >> 16) | (fbits(p3) & 0xffff0000u);
                    *(uint2*)(sb[qs] + wr_off[r]) = make_uint2(lo, hi);
                }

            const bf16x8 pa00 = *(const bf16x8*)(sb[0] + rd0);
            const bf16x8 pa01 = *(const bf16x8*)(sb[0] + rd1);
            const bf16x8 pa10 = *(const bf16x8*)(sb[1] + rd0);
            const bf16x8 pa11 = *(const bf16x8*)(sb[1] + rd1);
            #pragma unroll
            for (int jb = 0; jb < 4; ++jb) {
                const bf16x8 fb0 = *(const bf16x8*)(ftrA + half * 4096 + jb * 1024);
                const bf16x8 fb1 = *(const bf16x8*)(ftrB + half * 4096 + jb * 1024);
                ctx[0][jb] = __builtin_amdgcn_mfma_f32_16x16x32_bf16(pa00, fb0, ctx[0][jb], 0, 0, 0);
                ctx[0][jb] = __builtin_amdgcn_mfma_f32_16x16x32_bf16(pa01, fb1, ctx[0][jb], 0, 0, 0);
                ctx[1][jb] = __builtin_amdgcn_mfma_f32_16x16x32_bf16(pa10, fb0, ctx[1][jb], 0, 0, 0);
                ctx[1][jb] = __builtin_amdgcn_mfma_f32_16x16x32_bf16(pa11, fb1, ctx[1][jb], 0, 0, 0);
            }

            __syncthreads();
        }
    }

    #pragma unroll
    for (int qs = 0; qs < 2; ++qs)
        #pragma unroll
        for (int r = 0; r < 4; ++r) {
            float l = lsum[qs][r];
            #pragma unroll
            for (int off = 8; off; off >>= 1) l += __shfl_xor(l, off, 16);
            const float inv = 1.f / l;
            const int q = q0 + 32 * w + 16 * qs + quad * 4 + r;
            ushort* orow = hsa + (size_t)(b * S_ + q) * D_ + h * 64;
            #pragma unroll
            for (int jb = 0; jb < 4; ++jb)
                orow[16 * jb + ln] = f2bf(ctx[qs][jb][r] * inv);
        }
}

// ---------------------------------------------------------------------------
// gemm_ln: fh = hsa @ Wf, then out = LayerNorm(h + fh)*g + b — fused.
// Block = 32 m-rows x FULL 512 n (grid 256 = 1 block/CU). 4 waves split n.
// A: global->register double-buffer. B: LDS double-buffer, 512x32 tile,
// chunk swizzle phys = (quad + n + (n>>2)) & 3 (<=2-way, free).
// Epilogue: residual add, per-row mean/var via shfl + cross-wave LDS reduce,
// normalize, write final output. Removes ln_kernel + 48 MB fh round-trip.
// ---------------------------------------------------------------------------
__global__ __launch_bounds__(256, 1) void gemm_ln(
    const ushort* __restrict__ A, const ushort* __restrict__ WT,
    const float* __restrict__ h, const float* __restrict__ g,
    const float* __restrict__ bb, float* __restrict__ out)
{
    __shared__ ushort Bs[2][512 * 32];   // 64 KB
    __shared__ float red[32][8];         // [row][wave*2+{sum,sumsq}]

    const int tid = threadIdx.x;
    const int lane = tid & 63, w = tid >> 6;
    const int ln = lane & 15, quad = lane >> 4;
    const int m0 = blockIdx.x * 32;

    // B staging: 8 issues/wave, issue i covers rows w*128 + i*16 + (lane>>2)
    const int srow = lane >> 2;                      // 0..15
    const int pch = lane & 3;                        // phys chunk (DMA-fixed)
    const int lg = (pch - (srow & 3) - ((srow >> 2) & 3)) & 3;   // logical chunk
    const ushort* Bg[8];
    uint bo[8];
    #pragma unroll
    for (int i = 0; i < 8; ++i) {
        const int nrow = w * 128 + i * 16 + srow;
        Bg[i] = WT + (size_t)nrow * 512 + lg * 8;
        bo[i] = (w * 128 + i * 16) * 32 + lane * 8;  // wave-uniform base + lane*16B
    }
    // frag-read chunk: phys = (quad + ln + (ln>>2)) & 3
    const int prc = (quad + (ln & 3) + ((ln >> 2) & 3)) & 3;

    // A rows (register double-buffer)
    const ushort* Ar0 = A + (size_t)(m0 + ln) * 512 + quad * 8;
    const ushort* Ar1 = A + (size_t)(m0 + 16 + ln) * 512 + quad * 8;

    #pragma unroll
    for (int i = 0; i < 8; ++i) g2lds16(Bg[i], &Bs[0][bo[i]]);
    bf16x8 a_cur[2], a_nxt[2];
    a_cur[0] = *(const bf16x8*)Ar0;
    a_cur[1] = *(const bf16x8*)Ar1;

    f32x4 acc[2][8] = {};
    int buf = 0;
    for (int k0 = 0; k0 < 512; k0 += 32) {
        __syncthreads();
        if (k0 + 32 < 512) {
            #pragma unroll
            for (int i = 0; i < 8; ++i) g2lds16(Bg[i] + k0 + 32, &Bs[buf ^ 1][bo[i]]);
            a_nxt[0] = *(const bf16x8*)(Ar0 + k0 + 32);
            a_nxt[1] = *(const bf16x8*)(Ar1 + k0 + 32);
        }
        #pragma unroll
        for (int ni = 0; ni < 8; ++ni) {
            const bf16x8 bf = *(const bf16x8*)&Bs[buf][(w * 128 + ni * 16 + ln) * 32 + prc * 8];
            acc[0][ni] = __builtin_amdgcn_mfma_f32_16x16x32_bf16(a_cur[0], bf, acc[0][ni], 0, 0, 0);
            acc[1][ni] = __builtin_amdgcn_mfma_f32_16x16x32_bf16(a_cur[1], bf, acc[1][ni], 0, 0, 0);
        }
        a_cur[0] = a_nxt[0]; a_cur[1] = a_nxt[1];
        buf ^= 1;
    }

    // ---- epilogue: x = h + fh; LayerNorm over full rows ----
    #pragma unroll
    for (int mi = 0; mi < 2; ++mi)
        #pragma unroll
        for (int r = 0; r < 4; ++r) {
            const int row = m0 + mi * 16 + quad * 4 + r;
            #pragma unroll
            for (int ni = 0; ni < 8; ++ni)
                acc[mi][ni][r] += h[(size_t)row * 512 + w * 128 + ni * 16 + ln];
        }
    #pragma unroll
    for (int mi = 0; mi < 2; ++mi)
        #pragma unroll
        for (int r = 0; r < 4; ++r) {
            float s = 0.f, s2 = 0.f;
            #pragma unroll
            for (int ni = 0; ni < 8; ++ni) {
                const float x = acc[mi][ni][r];
                s += x; s2 += x * x;
            }
            #pragma unroll
            for (int off = 8; off; off >>= 1) {
                s += __shfl_xor(s, off, 16);
                s2 += __shfl_xor(s2, off, 16);
            }
            if (ln == 0) {
                red[mi * 16 + quad * 4 + r][w * 2] = s;
                red[mi * 16 + quad * 4 + r][w * 2 + 1] = s2;
            }
        }
    __syncthreads();

    float gv[8], bv[8];
    #pragma unroll
    for (int ni = 0; ni < 8; ++ni) {
        gv[ni] = g[w * 128 + ni * 16 + ln];
        bv[ni] = bb[w * 128 + ni * 16 + ln];
    }
    #pragma unroll
    for (int mi = 0; mi < 2; ++mi)
        #pragma unroll
        for (int r = 0; r < 4; ++r) {
            const int lrow = mi * 16 + quad * 4 + r;
            const float S  = red[lrow][0] + red[lrow][2] + red[lrow][4] + red[lrow][6];
            const float S2 = red[lrow][1] + red[lrow][3] + red[lrow][5] + red[lrow][7];
            const float mu = S * (1.f / 512.f);
            const float inv = rsqrtf(S2 * (1.f / 512.f) - mu * mu + LN_EPS);
            const size_t rb = (size_t)(m0 + lrow) * 512 + w * 128;
            #pragma unroll
            for (int ni = 0; ni < 8; ++ni)
                out[rb + ni * 16 + ln] = (acc[mi][ni][r] - mu) * inv * gv[ni] + bv[ni];
        }
}

// ---------------------------------------------------------------------------
extern "C" void kernel_launch(void* const* d_in, const int* in_sizes, int n_in,
                              void* d_out, int out_size, void* d_ws, size_t ws_size,
                              hipStream_t stream)
{
    const float* h   = (const float*)d_in[0];
    const float* rh  = (const float*)d_in[1];
    // d_in[2] = Wl, d_in[4] = al : unused — sl cancels in softmax
    const float* Wr  = (const float*)d_in[3];
    const float* ar  = (const float*)d_in[5];
    const float* Wrs = (const float*)d_in[6];
    const float* Wrt = (const float*)d_in[7];
    const float* Wf  = (const float*)d_in[8];
    const float* lng = (const float*)d_in[9];
    const float* lnb = (const float*)d_in[10];
    float* out = (float*)d_out;
    char* wsb  = (char*)d_ws;

    const size_t MB = (size_t)1 << 20;
    ushort* hb   = (ushort*)(wsb);               //  8 MB
    ushort* rhb  = (ushort*)(wsb + 8 * MB);      //  1 MB
    ushort* WrT  = (ushort*)(wsb + 9 * MB);      // .5 MB
    ushort* WfT  = (ushort*)(wsb + 9 * MB + 512 * 1024);
    ushort* WrsT = (ushort*)(wsb + 10 * MB);     // 64 KB
    ushort* WrtT = (ushort*)(wsb + 10 * MB + 64 * 1024);
    ushort* frT  = (ushort*)(wsb + 11 * MB);     //  8 MB  [B,H,64,S]
    ushort* rkw  = (ushort*)(wsb + 19 * MB);     //  8 MB  [B,H,S,64]
    ushort* rqw  = (ushort*)(wsb + 27 * MB);     //  8 MB  [B,H,S,64]
    float*  sr   = (float*) (wsb + 35 * MB);     // .25MB  [B,H,S]
    ushort* hsab = (ushort*)(wsb + 36 * MB);     //  8 MB  [B,S,512] bf16

    dim3 blk(256);
    prep<<<dim3(4752), blk, 0, stream>>>(h, rh, Wr, Wf, Wrs, Wrt,
                                         hb, rhb, WrT, WfT, WrsT, WrtT);
    proj<<<dim3(128, 4, 3), blk, 0, stream>>>(hb, rhb, WrT, WrsT, WrtT,
                                              frT, rkw, rqw, sr, ar);
    attn_mfma<<<dim3(S_ / 128, H_, B_), blk, 0, stream>>>(frT, rkw, rqw, sr, hsab);
    gemm_ln<<<dim3(256), blk, 0, stream>>>(hsab, WfT, h, lng, lnb, out);
}